// Round 2
// baseline (442.708 us; speedup 1.0000x reference)
//
#include <hip/hip_runtime.h>
#include <hip/hip_bf16.h>
#include <math.h>

typedef __attribute__((ext_vector_type(8))) short short8;
typedef __attribute__((ext_vector_type(4))) float floatx4;

#define D_MODEL 1024
#define NHEAD   16
#define HD      64
#define BATCH   4
#define SEQ     2048
#define M_TOT   (BATCH * SEQ)  // 8192

__device__ __forceinline__ unsigned short f2bf(float f) {
  unsigned int u = __builtin_bit_cast(unsigned int, f);
  u += 0x7FFFu + ((u >> 16) & 1u);
  return (unsigned short)(u >> 16);
}

// ---------------- convert X (fp32 -> bf16) ----------------
__global__ __launch_bounds__(256) void cvt_x_kernel(const float* __restrict__ X,
                                                    unsigned short* __restrict__ Xb) {
  int i = blockIdx.x * 256 + threadIdx.x;  // one float4 per thread
  float4 v = reinterpret_cast<const float4*>(X)[i];
  ushort4 o;
  o.x = f2bf(v.x); o.y = f2bf(v.y); o.z = f2bf(v.z); o.w = f2bf(v.w);
  reinterpret_cast<ushort4*>(Xb)[i] = o;
}

// ---------------- convert + transpose W (fp32 [K][N] -> bf16 [N][K]) ----------------
__global__ __launch_bounds__(256) void cvt_wt_kernel(const float* __restrict__ W0,
                                                     const float* __restrict__ W1,
                                                     const float* __restrict__ W2,
                                                     const float* __restrict__ W3,
                                                     unsigned short* __restrict__ T0,
                                                     unsigned short* __restrict__ T1,
                                                     unsigned short* __restrict__ T2,
                                                     unsigned short* __restrict__ T3) {
  const float* W;
  unsigned short* T;
  switch (blockIdx.z) {
    case 0: W = W0; T = T0; break;
    case 1: W = W1; T = T1; break;
    case 2: W = W2; T = T2; break;
    default: W = W3; T = T3; break;
  }
  __shared__ unsigned short tile[64][65];
  int n0 = blockIdx.x * 64, k0 = blockIdx.y * 64;
#pragma unroll
  for (int i = 0; i < 16; ++i) {
    int e = threadIdx.x + i * 256;
    int r = e >> 6, c = e & 63;
    tile[r][c] = f2bf(W[(size_t)(k0 + r) * D_MODEL + n0 + c]);
  }
  __syncthreads();
#pragma unroll
  for (int i = 0; i < 16; ++i) {
    int e = threadIdx.x + i * 256;
    int r = e >> 6, c = e & 63;
    T[(size_t)(n0 + r) * D_MODEL + k0 + c] = tile[c][r];
  }
}

// ---------------- fused QKV GEMM ----------------
// C = Xb[M][K] @ W (via Wt[N][K]) + bias, scaled; written as [B,H,S,hd] bf16.
__global__ __launch_bounds__(256) void qkv_gemm_kernel(
    const unsigned short* __restrict__ Xb,
    const unsigned short* __restrict__ WqT, const unsigned short* __restrict__ WkT,
    const unsigned short* __restrict__ WvT,
    const float* __restrict__ bq, const float* __restrict__ bk, const float* __restrict__ bv,
    unsigned short* __restrict__ Qo, unsigned short* __restrict__ Ko,
    unsigned short* __restrict__ Vo) {
  const unsigned short* Bt;
  const float* bias;
  unsigned short* Out;
  float scale;
  if (blockIdx.z == 0)      { Bt = WqT; bias = bq; Out = Qo; scale = 0.125f; }
  else if (blockIdx.z == 1) { Bt = WkT; bias = bk; Out = Ko; scale = 1.0f; }
  else                      { Bt = WvT; bias = bv; Out = Vo; scale = 1.0f; }

  __shared__ unsigned short As[128][72];
  __shared__ unsigned short Bs[128][72];

  int m0 = blockIdx.x * 128, n0 = blockIdx.y * 128;
  int tid = threadIdx.x;
  int lane = tid & 63;
  int wid = tid >> 6;
  int wr = (wid >> 1) * 64, wc = (wid & 1) * 64;
  int l15 = lane & 15, lg = lane >> 4;

  floatx4 acc[4][4];
#pragma unroll
  for (int mi = 0; mi < 4; ++mi)
#pragma unroll
    for (int ni = 0; ni < 4; ++ni)
#pragma unroll
      for (int e = 0; e < 4; ++e) acc[mi][ni][e] = 0.0f;

  for (int kt = 0; kt < D_MODEL / 64; ++kt) {
    int k0 = kt * 64;
#pragma unroll
    for (int i = 0; i < 4; ++i) {
      int e = tid + i * 256;
      int row = e >> 3, cb = (e & 7) * 8;
      *reinterpret_cast<short8*>(&As[row][cb]) =
          *reinterpret_cast<const short8*>(&Xb[(size_t)(m0 + row) * D_MODEL + k0 + cb]);
      *reinterpret_cast<short8*>(&Bs[row][cb]) =
          *reinterpret_cast<const short8*>(&Bt[(size_t)(n0 + row) * D_MODEL + k0 + cb]);
    }
    __syncthreads();
#pragma unroll
    for (int kk = 0; kk < 2; ++kk) {
      int col = kk * 32 + lg * 8;
      short8 af[4], bf[4];
#pragma unroll
      for (int mi = 0; mi < 4; ++mi)
        af[mi] = *reinterpret_cast<const short8*>(&As[wr + mi * 16 + l15][col]);
#pragma unroll
      for (int ni = 0; ni < 4; ++ni)
        bf[ni] = *reinterpret_cast<const short8*>(&Bs[wc + ni * 16 + l15][col]);
#pragma unroll
      for (int mi = 0; mi < 4; ++mi)
#pragma unroll
        for (int ni = 0; ni < 4; ++ni)
          acc[mi][ni] =
              __builtin_amdgcn_mfma_f32_16x16x32_bf16(af[mi], bf[ni], acc[mi][ni], 0, 0, 0);
    }
    __syncthreads();
  }

#pragma unroll
  for (int mi = 0; mi < 4; ++mi)
#pragma unroll
    for (int ni = 0; ni < 4; ++ni) {
      int n = n0 + wc + ni * 16 + l15;
      float bia = bias[n];
      int h = n >> 6, d = n & 63;
#pragma unroll
      for (int r = 0; r < 4; ++r) {
        int m = m0 + wr + mi * 16 + lg * 4 + r;
        int b = m >> 11, s = m & 2047;
        float val = (acc[mi][ni][r] + bia) * scale;
        Out[(((size_t)(b * NHEAD + h)) * SEQ + s) * HD + d] = f2bf(val);
      }
    }
}

// ---------------- causal flash attention ----------------
// Q,K,V: [B*H][S][64] bf16 (Q pre-scaled by 1/8). ctx out: [B][S][D] bf16.
__global__ __launch_bounds__(256) void attn_kernel(const unsigned short* __restrict__ Q,
                                                   const unsigned short* __restrict__ K,
                                                   const unsigned short* __restrict__ V,
                                                   unsigned short* __restrict__ ctx) {
  __shared__ unsigned short Ks[64][72];
  __shared__ unsigned short Vt[64][72];   // Vt[d][key]
  __shared__ unsigned short Ps[4][16][72];

  int qt = blockIdx.x;          // q tile (64 rows)
  int bh = blockIdx.y;          // b*16+h
  int q0 = qt * 64;
  int tid = threadIdx.x;
  int lane = tid & 63;
  int w = tid >> 6;
  int l15 = lane & 15, lg = lane >> 4;

  const unsigned short* Qb = Q + (size_t)bh * SEQ * HD;
  const unsigned short* Kb = K + (size_t)bh * SEQ * HD;
  const unsigned short* Vb = V + (size_t)bh * SEQ * HD;

  // Q fragments for this wave's 16 rows
  short8 qf[2];
  int qrowA = q0 + w * 16 + l15;
#pragma unroll
  for (int kk = 0; kk < 2; ++kk)
    qf[kk] = *reinterpret_cast<const short8*>(&Qb[(size_t)qrowA * HD + kk * 32 + lg * 8]);

  floatx4 oacc[4];
#pragma unroll
  for (int ni = 0; ni < 4; ++ni)
#pragma unroll
    for (int e = 0; e < 4; ++e) oacc[ni][e] = 0.0f;
  float mrow[4], lrow[4];
#pragma unroll
  for (int r = 0; r < 4; ++r) { mrow[r] = -INFINITY; lrow[r] = 0.0f; }

  for (int kt = 0; kt <= qt; ++kt) {
    int kb0 = kt * 64;
    // stage K tile: rows=key, cols=d (coalesced)
#pragma unroll
    for (int i = 0; i < 2; ++i) {
      int e = tid + i * 256;
      int row = e >> 3, cb = (e & 7) * 8;
      *reinterpret_cast<short8*>(&Ks[row][cb]) =
          *reinterpret_cast<const short8*>(&Kb[(size_t)(kb0 + row) * HD + cb]);
    }
    // stage V transposed: Vt[d][key]; LDS writes contiguous across threads
#pragma unroll
    for (int i = 0; i < 2; ++i) {
      int e = tid + i * 256;
      int key = e & 63, db = e >> 6;  // db in 0..7
      short8 v = *reinterpret_cast<const short8*>(&Vb[(size_t)(kb0 + key) * HD + db * 8]);
#pragma unroll
      for (int j = 0; j < 8; ++j) Vt[db * 8 + j][key] = (unsigned short)v[j];
    }
    __syncthreads();

    // scores: 16 q-rows x 64 keys per wave
    floatx4 sf[4];
#pragma unroll
    for (int nk = 0; nk < 4; ++nk)
#pragma unroll
      for (int e = 0; e < 4; ++e) sf[nk][e] = 0.0f;
    int colk = lg * 8;
#pragma unroll
    for (int nk = 0; nk < 4; ++nk) {
      short8 kf0 = *reinterpret_cast<const short8*>(&Ks[nk * 16 + l15][colk]);
      short8 kf1 = *reinterpret_cast<const short8*>(&Ks[nk * 16 + l15][32 + colk]);
      sf[nk] = __builtin_amdgcn_mfma_f32_16x16x32_bf16(qf[0], kf0, sf[nk], 0, 0, 0);
      sf[nk] = __builtin_amdgcn_mfma_f32_16x16x32_bf16(qf[1], kf1, sf[nk], 0, 0, 0);
    }

    if (kt == qt) {  // causal mask on diagonal tile
#pragma unroll
      for (int nk = 0; nk < 4; ++nk) {
        int key = kb0 + nk * 16 + l15;
#pragma unroll
        for (int r = 0; r < 4; ++r) {
          int qr = q0 + w * 16 + lg * 4 + r;
          if (key > qr) sf[nk][r] = -INFINITY;
        }
      }
    }

    // online softmax (rows live across 16-lane groups; reduce over l&15)
    float p[4][4];  // [nk][r]
#pragma unroll
    for (int r = 0; r < 4; ++r) {
      float mx = fmaxf(fmaxf(sf[0][r], sf[1][r]), fmaxf(sf[2][r], sf[3][r]));
      mx = fmaxf(mx, __shfl_xor(mx, 1));
      mx = fmaxf(mx, __shfl_xor(mx, 2));
      mx = fmaxf(mx, __shfl_xor(mx, 4));
      mx = fmaxf(mx, __shfl_xor(mx, 8));
      float nm = fmaxf(mrow[r], mx);
      float sc = __expf(mrow[r] - nm);
      float ts = 0.0f;
#pragma unroll
      for (int nk = 0; nk < 4; ++nk) {
        float pe = __expf(sf[nk][r] - nm);
        p[nk][r] = pe;
        ts += pe;
      }
      ts += __shfl_xor(ts, 1);
      ts += __shfl_xor(ts, 2);
      ts += __shfl_xor(ts, 4);
      ts += __shfl_xor(ts, 8);
      lrow[r] = lrow[r] * sc + ts;
      mrow[r] = nm;
#pragma unroll
      for (int ni = 0; ni < 4; ++ni) oacc[ni][r] *= sc;
    }

    // P -> LDS (relayout D-frag -> A-frag)
#pragma unroll
    for (int nk = 0; nk < 4; ++nk)
#pragma unroll
      for (int r = 0; r < 4; ++r)
        Ps[w][lg * 4 + r][nk * 16 + l15] = f2bf(p[nk][r]);

    // PV
#pragma unroll
    for (int kk2 = 0; kk2 < 2; ++kk2) {
      short8 pa = *reinterpret_cast<const short8*>(&Ps[w][l15][kk2 * 32 + colk]);
#pragma unroll
      for (int ni = 0; ni < 4; ++ni) {
        short8 vf = *reinterpret_cast<const short8*>(&Vt[ni * 16 + l15][kk2 * 32 + colk]);
        oacc[ni] = __builtin_amdgcn_mfma_f32_16x16x32_bf16(pa, vf, oacc[ni], 0, 0, 0);
      }
    }
    __syncthreads();
  }

  // epilogue: ctx[b][s][h*64+d] bf16
  int b = bh >> 4, h = bh & 15;
#pragma unroll
  for (int ni = 0; ni < 4; ++ni) {
    int d = ni * 16 + l15;
#pragma unroll
    for (int r = 0; r < 4; ++r) {
      int qr = q0 + w * 16 + lg * 4 + r;
      float val = oacc[ni][r] / lrow[r];
      ctx[((size_t)(b * SEQ + qr)) * D_MODEL + h * HD + d] = f2bf(val);
    }
  }
}

// ---------------- output projection GEMM (bf16 ctx @ Wo + bo -> fp32) ----------------
__global__ __launch_bounds__(256) void out_gemm_kernel(const unsigned short* __restrict__ A,
                                                       const unsigned short* __restrict__ Bt,
                                                       const float* __restrict__ bias,
                                                       float* __restrict__ Out) {
  __shared__ unsigned short As[128][72];
  __shared__ unsigned short Bs[128][72];

  int m0 = blockIdx.x * 128, n0 = blockIdx.y * 128;
  int tid = threadIdx.x;
  int lane = tid & 63;
  int wid = tid >> 6;
  int wr = (wid >> 1) * 64, wc = (wid & 1) * 64;
  int l15 = lane & 15, lg = lane >> 4;

  floatx4 acc[4][4];
#pragma unroll
  for (int mi = 0; mi < 4; ++mi)
#pragma unroll
    for (int ni = 0; ni < 4; ++ni)
#pragma unroll
      for (int e = 0; e < 4; ++e) acc[mi][ni][e] = 0.0f;

  for (int kt = 0; kt < D_MODEL / 64; ++kt) {
    int k0 = kt * 64;
#pragma unroll
    for (int i = 0; i < 4; ++i) {
      int e = tid + i * 256;
      int row = e >> 3, cb = (e & 7) * 8;
      *reinterpret_cast<short8*>(&As[row][cb]) =
          *reinterpret_cast<const short8*>(&A[(size_t)(m0 + row) * D_MODEL + k0 + cb]);
      *reinterpret_cast<short8*>(&Bs[row][cb]) =
          *reinterpret_cast<const short8*>(&Bt[(size_t)(n0 + row) * D_MODEL + k0 + cb]);
    }
    __syncthreads();
#pragma unroll
    for (int kk = 0; kk < 2; ++kk) {
      int col = kk * 32 + lg * 8;
      short8 af[4], bf[4];
#pragma unroll
      for (int mi = 0; mi < 4; ++mi)
        af[mi] = *reinterpret_cast<const short8*>(&As[wr + mi * 16 + l15][col]);
#pragma unroll
      for (int ni = 0; ni < 4; ++ni)
        bf[ni] = *reinterpret_cast<const short8*>(&Bs[wc + ni * 16 + l15][col]);
#pragma unroll
      for (int mi = 0; mi < 4; ++mi)
#pragma unroll
        for (int ni = 0; ni < 4; ++ni)
          acc[mi][ni] =
              __builtin_amdgcn_mfma_f32_16x16x32_bf16(af[mi], bf[ni], acc[mi][ni], 0, 0, 0);
    }
    __syncthreads();
  }

#pragma unroll
  for (int mi = 0; mi < 4; ++mi)
#pragma unroll
    for (int ni = 0; ni < 4; ++ni) {
      int n = n0 + wc + ni * 16 + l15;
      float bia = bias[n];
#pragma unroll
      for (int r = 0; r < 4; ++r) {
        int m = m0 + wr + mi * 16 + lg * 4 + r;
        Out[(size_t)m * D_MODEL + n] = acc[mi][ni][r] + bia;
      }
    }
}

extern "C" void kernel_launch(void* const* d_in, const int* in_sizes, int n_in,
                              void* d_out, int out_size, void* d_ws, size_t ws_size,
                              hipStream_t stream) {
  const float* X  = (const float*)d_in[0];
  const float* Wq = (const float*)d_in[1];
  const float* bq = (const float*)d_in[2];
  const float* Wk = (const float*)d_in[3];
  const float* bk = (const float*)d_in[4];
  const float* Wv = (const float*)d_in[5];
  const float* bv = (const float*)d_in[6];
  const float* Wo = (const float*)d_in[7];
  const float* bo = (const float*)d_in[8];
  float* out = (float*)d_out;

  char* ws = (char*)d_ws;
  const size_t MB = 1024 * 1024;
  unsigned short* Xb   = (unsigned short*)(ws);
  unsigned short* WqT  = (unsigned short*)(ws + 16 * MB);
  unsigned short* WkT  = (unsigned short*)(ws + 18 * MB);
  unsigned short* WvT  = (unsigned short*)(ws + 20 * MB);
  unsigned short* WoT  = (unsigned short*)(ws + 22 * MB);
  unsigned short* Qw   = (unsigned short*)(ws + 24 * MB);
  unsigned short* Kw   = (unsigned short*)(ws + 40 * MB);
  unsigned short* Vw   = (unsigned short*)(ws + 56 * MB);
  unsigned short* Ctx  = (unsigned short*)(ws + 72 * MB);

  // 1. converts
  cvt_x_kernel<<<(M_TOT * D_MODEL / 4) / 256, 256, 0, stream>>>(X, Xb);
  cvt_wt_kernel<<<dim3(16, 16, 4), 256, 0, stream>>>(Wq, Wk, Wv, Wo, WqT, WkT, WvT, WoT);
  // 2. QKV projections
  qkv_gemm_kernel<<<dim3(M_TOT / 128, D_MODEL / 128, 3), 256, 0, stream>>>(
      Xb, WqT, WkT, WvT, bq, bk, bv, Qw, Kw, Vw);
  // 3. causal flash attention
  attn_kernel<<<dim3(SEQ / 64, BATCH * NHEAD), 256, 0, stream>>>(Qw, Kw, Vw, Ctx);
  // 4. output projection
  out_gemm_kernel<<<dim3(M_TOT / 128, D_MODEL / 128), 256, 0, stream>>>(Ctx, WoT, bo, out);
}

// Round 3
// 424.204 us; speedup vs baseline: 1.0436x; 1.0436x over previous
//
#include <hip/hip_runtime.h>
#include <hip/hip_bf16.h>
#include <math.h>

typedef __attribute__((ext_vector_type(8))) short short8;
typedef __attribute__((ext_vector_type(4))) float floatx4;

#define D_MODEL 1024
#define NHEAD   16
#define HD      64
#define BATCH   4
#define SEQ     2048
#define M_TOT   (BATCH * SEQ)  // 8192

__device__ __forceinline__ unsigned short f2bf(float f) {
  unsigned int u = __builtin_bit_cast(unsigned int, f);
  u += 0x7FFFu + ((u >> 16) & 1u);
  return (unsigned short)(u >> 16);
}

// async global->LDS, 16B per lane. lds base must be wave-uniform; content lands
// at base + lane*16 (linear). Swizzle achieved by pre-swizzling the GLOBAL src.
__device__ __forceinline__ void gl_lds16(const void* g, void* l) {
  __builtin_amdgcn_global_load_lds((__attribute__((address_space(1))) void*)g,
                                   (__attribute__((address_space(3))) void*)l,
                                   16, 0, 0);
}

// ---------------- convert X (fp32 -> bf16) ----------------
__global__ __launch_bounds__(256) void cvt_x_kernel(const float* __restrict__ X,
                                                    unsigned short* __restrict__ Xb) {
  int i = blockIdx.x * 256 + threadIdx.x;
  float4 v = reinterpret_cast<const float4*>(X)[i];
  ushort4 o;
  o.x = f2bf(v.x); o.y = f2bf(v.y); o.z = f2bf(v.z); o.w = f2bf(v.w);
  reinterpret_cast<ushort4*>(Xb)[i] = o;
}

// ---------------- convert + transpose W (fp32 [K][N] -> bf16 [N][K]) ----------------
__global__ __launch_bounds__(256) void cvt_wt_kernel(const float* __restrict__ W0,
                                                     const float* __restrict__ W1,
                                                     const float* __restrict__ W2,
                                                     const float* __restrict__ W3,
                                                     unsigned short* __restrict__ T0,
                                                     unsigned short* __restrict__ T1,
                                                     unsigned short* __restrict__ T2,
                                                     unsigned short* __restrict__ T3) {
  const float* W;
  unsigned short* T;
  switch (blockIdx.z) {
    case 0: W = W0; T = T0; break;
    case 1: W = W1; T = T1; break;
    case 2: W = W2; T = T2; break;
    default: W = W3; T = T3; break;
  }
  __shared__ unsigned short tile[64][65];
  int n0 = blockIdx.x * 64, k0 = blockIdx.y * 64;
#pragma unroll
  for (int i = 0; i < 16; ++i) {
    int e = threadIdx.x + i * 256;
    int r = e >> 6, c = e & 63;
    tile[r][c] = f2bf(W[(size_t)(k0 + r) * D_MODEL + n0 + c]);
  }
  __syncthreads();
#pragma unroll
  for (int i = 0; i < 16; ++i) {
    int e = threadIdx.x + i * 256;
    int r = e >> 6, c = e & 63;
    T[(size_t)(n0 + r) * D_MODEL + k0 + c] = tile[c][r];
  }
}

// ---------------- fused QKV GEMM (m97 structure: global_load_lds + swizzle) ----
// C = Xb[M][K] @ W (via Wt[N][K]) + bias; Q,K written [B,H,S,hd]; V written
// TRANSPOSED [B,H,hd,S] so attention can stage V^T coalesced.
__global__ __launch_bounds__(256) void qkv_gemm_kernel(
    const unsigned short* __restrict__ Xb,
    const unsigned short* __restrict__ WqT, const unsigned short* __restrict__ WkT,
    const unsigned short* __restrict__ WvT,
    const float* __restrict__ bq, const float* __restrict__ bk, const float* __restrict__ bv,
    unsigned short* __restrict__ Qo, unsigned short* __restrict__ Ko,
    unsigned short* __restrict__ Vo) {
  const unsigned short* Bt;
  const float* bias;
  unsigned short* Out;
  float scale;
  if (blockIdx.z == 0)      { Bt = WqT; bias = bq; Out = Qo; scale = 0.125f; }
  else if (blockIdx.z == 1) { Bt = WkT; bias = bk; Out = Ko; scale = 1.0f; }
  else                      { Bt = WvT; bias = bv; Out = Vo; scale = 1.0f; }

  __shared__ unsigned short As[128 * 64];
  __shared__ unsigned short Bs[128 * 64];

  int m0 = blockIdx.x * 128, n0 = blockIdx.y * 128;
  int tid = threadIdx.x;
  int lane = tid & 63;
  int w = tid >> 6;
  int wr = (w >> 1) * 64, wc = (w & 1) * 64;
  int l15 = lane & 15, lg = lane >> 4;
  int lr8 = lane >> 3, lc8 = lane & 7;  // staging row-in-chunk / slot

  floatx4 acc[4][4];
#pragma unroll
  for (int mi = 0; mi < 4; ++mi)
#pragma unroll
    for (int ni = 0; ni < 4; ++ni)
#pragma unroll
      for (int e = 0; e < 4; ++e) acc[mi][ni][e] = 0.0f;

  for (int kt = 0; kt < D_MODEL / 64; ++kt) {
    int k0 = kt * 64;
#pragma unroll
    for (int i = 0; i < 4; ++i) {
      int c = w + i * 4;            // chunk 0..15, 8 rows each
      int r = c * 8 + lr8;
      int blk = lc8 ^ (r & 7);      // pre-swizzled source slot
      gl_lds16(&Xb[(size_t)(m0 + r) * D_MODEL + k0 + blk * 8], &As[c * 512]);
      gl_lds16(&Bt[(size_t)(n0 + r) * D_MODEL + k0 + blk * 8], &Bs[c * 512]);
    }
    __syncthreads();
#pragma unroll
    for (int kk = 0; kk < 2; ++kk) {
      short8 af[4], bf[4];
#pragma unroll
      for (int mi = 0; mi < 4; ++mi) {
        int row = wr + mi * 16 + l15;
        int col = (kk * 32 + lg * 8) ^ ((row & 7) << 3);
        af[mi] = *reinterpret_cast<const short8*>(&As[row * 64 + col]);
      }
#pragma unroll
      for (int ni = 0; ni < 4; ++ni) {
        int row = wc + ni * 16 + l15;
        int col = (kk * 32 + lg * 8) ^ ((row & 7) << 3);
        bf[ni] = *reinterpret_cast<const short8*>(&Bs[row * 64 + col]);
      }
#pragma unroll
      for (int mi = 0; mi < 4; ++mi)
#pragma unroll
        for (int ni = 0; ni < 4; ++ni)
          acc[mi][ni] =
              __builtin_amdgcn_mfma_f32_16x16x32_bf16(af[mi], bf[ni], acc[mi][ni], 0, 0, 0);
    }
    __syncthreads();
  }

  bool vout = (blockIdx.z == 2);
#pragma unroll
  for (int mi = 0; mi < 4; ++mi)
#pragma unroll
    for (int ni = 0; ni < 4; ++ni) {
      int n = n0 + wc + ni * 16 + l15;
      float bia = bias[n];
      int h = n >> 6, d = n & 63;
#pragma unroll
      for (int r = 0; r < 4; ++r) {
        int m = m0 + wr + mi * 16 + lg * 4 + r;
        int b = m >> 11, s = m & 2047;
        float val = (acc[mi][ni][r] + bia) * scale;
        size_t idx;
        if (vout)  // V^T: [bh][d][s]
          idx = (((size_t)(b * NHEAD + h)) * HD + d) * SEQ + s;
        else       // Q,K: [bh][s][d]
          idx = (((size_t)(b * NHEAD + h)) * SEQ + s) * HD + d;
        Out[idx] = f2bf(val);
      }
    }
}

// ---------------- causal flash attention (128 q-rows/block, dbuf K/V) --------
// Q,K: [B*H][S][64] bf16 (Q pre-scaled 1/8); Vt: [B*H][64][S]; ctx: [B][S][D] bf16.
__global__ __launch_bounds__(256) void attn_kernel(const unsigned short* __restrict__ Q,
                                                   const unsigned short* __restrict__ K,
                                                   const unsigned short* __restrict__ Vt,
                                                   unsigned short* __restrict__ ctx) {
  __shared__ unsigned short Ks[2][64 * 64];
  __shared__ unsigned short Vs[2][64 * 64];
  __shared__ unsigned short Ps[4][32 * 64];

  int qt = (int)gridDim.x - 1 - (int)blockIdx.x;  // longest blocks first
  int bh = blockIdx.y;
  int q0 = qt * 128;
  int tid = threadIdx.x;
  int lane = tid & 63;
  int w = tid >> 6;
  int l15 = lane & 15, lg = lane >> 4;
  int lr8 = lane >> 3, lc8 = lane & 7;

  const unsigned short* Qb = Q + (size_t)bh * SEQ * HD;
  const unsigned short* Kb = K + (size_t)bh * SEQ * HD;
  const unsigned short* Vb = Vt + (size_t)bh * HD * SEQ;

  // Q fragments: wave w owns q rows q0 + w*32 .. +31 (2 m-frags of 16)
  short8 qf[2][2];
#pragma unroll
  for (int mf = 0; mf < 2; ++mf)
#pragma unroll
    for (int kk = 0; kk < 2; ++kk)
      qf[mf][kk] = *reinterpret_cast<const short8*>(
          &Qb[(size_t)(q0 + w * 32 + mf * 16 + l15) * HD + kk * 32 + lg * 8]);

  floatx4 oacc[2][4];
#pragma unroll
  for (int mf = 0; mf < 2; ++mf)
#pragma unroll
    for (int ni = 0; ni < 4; ++ni)
#pragma unroll
      for (int e = 0; e < 4; ++e) oacc[mf][ni][e] = 0.0f;
  float mrow[2][4], lrow[2][4];
#pragma unroll
  for (int mf = 0; mf < 2; ++mf)
#pragma unroll
    for (int r = 0; r < 4; ++r) { mrow[mf][r] = -INFINITY; lrow[mf][r] = 0.0f; }

  int nt = 2 * qt + 2;

  // prologue: stage tile 0 into buf 0
  {
    const unsigned short* kg = Kb;
    const unsigned short* vg = Vb;
#pragma unroll
    for (int i = 0; i < 2; ++i) {
      int c = w + i * 4;
      int r = c * 8 + lr8;
      int blk = lc8 ^ (r & 7);
      gl_lds16(&kg[(size_t)r * HD + blk * 8], &Ks[0][c * 512]);
      gl_lds16(&vg[(size_t)r * SEQ + blk * 8], &Vs[0][c * 512]);
    }
  }
  __syncthreads();

  for (int t = 0; t < nt; ++t) {
    int buf = t & 1;
    // prefetch next tile into buf^1 (loads stay in flight during compute)
    if (t + 1 < nt) {
      int kb1 = (t + 1) * 64;
      const unsigned short* kg = Kb + (size_t)kb1 * HD;
      const unsigned short* vg = Vb + kb1;
#pragma unroll
      for (int i = 0; i < 2; ++i) {
        int c = w + i * 4;
        int r = c * 8 + lr8;
        int blk = lc8 ^ (r & 7);
        gl_lds16(&kg[(size_t)r * HD + blk * 8], &Ks[buf ^ 1][c * 512]);
        gl_lds16(&vg[(size_t)r * SEQ + blk * 8], &Vs[buf ^ 1][c * 512]);
      }
    }

    // ---- QK^T ----
    short8 kf[4][2];
#pragma unroll
    for (int nk = 0; nk < 4; ++nk)
#pragma unroll
      for (int kk = 0; kk < 2; ++kk) {
        int row = nk * 16 + l15;
        int col = (kk * 32 + lg * 8) ^ ((row & 7) << 3);
        kf[nk][kk] = *reinterpret_cast<const short8*>(&Ks[buf][row * 64 + col]);
      }
    floatx4 sf[2][4];
#pragma unroll
    for (int mf = 0; mf < 2; ++mf)
#pragma unroll
      for (int nk = 0; nk < 4; ++nk) {
#pragma unroll
        for (int e = 0; e < 4; ++e) sf[mf][nk][e] = 0.0f;
        sf[mf][nk] = __builtin_amdgcn_mfma_f32_16x16x32_bf16(qf[mf][0], kf[nk][0], sf[mf][nk], 0, 0, 0);
        sf[mf][nk] = __builtin_amdgcn_mfma_f32_16x16x32_bf16(qf[mf][1], kf[nk][1], sf[mf][nk], 0, 0, 0);
      }

    // causal mask (only the last two tiles can straddle the diagonal)
    if (t >= nt - 2) {
      int kb0 = t * 64;
#pragma unroll
      for (int mf = 0; mf < 2; ++mf)
#pragma unroll
        for (int nk = 0; nk < 4; ++nk) {
          int key = kb0 + nk * 16 + l15;
#pragma unroll
          for (int r = 0; r < 4; ++r) {
            int qr = q0 + w * 32 + mf * 16 + lg * 4 + r;
            if (key > qr) sf[mf][nk][r] = -INFINITY;
          }
        }
    }

    // ---- online softmax (reduce across the 16-lane col groups) ----
#pragma unroll
    for (int mf = 0; mf < 2; ++mf)
#pragma unroll
      for (int r = 0; r < 4; ++r) {
        float mx = fmaxf(fmaxf(sf[mf][0][r], sf[mf][1][r]),
                         fmaxf(sf[mf][2][r], sf[mf][3][r]));
        mx = fmaxf(mx, __shfl_xor(mx, 1));
        mx = fmaxf(mx, __shfl_xor(mx, 2));
        mx = fmaxf(mx, __shfl_xor(mx, 4));
        mx = fmaxf(mx, __shfl_xor(mx, 8));
        float nm = fmaxf(mrow[mf][r], mx);
        float sc = __expf(mrow[mf][r] - nm);
        float ts = 0.0f;
        int prow = mf * 16 + lg * 4 + r;           // row within wave's 32
        int pswz = (prow & 7) << 3;
#pragma unroll
        for (int nk = 0; nk < 4; ++nk) {
          float pe = __expf(sf[mf][nk][r] - nm);
          ts += pe;
          Ps[w][prow * 64 + ((nk * 16 + l15) ^ pswz)] = f2bf(pe);
        }
        ts += __shfl_xor(ts, 1);
        ts += __shfl_xor(ts, 2);
        ts += __shfl_xor(ts, 4);
        ts += __shfl_xor(ts, 8);
        lrow[mf][r] = lrow[mf][r] * sc + ts;
        mrow[mf][r] = nm;
#pragma unroll
        for (int ni = 0; ni < 4; ++ni) oacc[mf][ni][r] *= sc;
      }

    // ---- PV ----
    short8 vf[4][2];
#pragma unroll
    for (int ni = 0; ni < 4; ++ni)
#pragma unroll
      for (int kk = 0; kk < 2; ++kk) {
        int row = ni * 16 + l15;
        int col = (kk * 32 + lg * 8) ^ ((row & 7) << 3);
        vf[ni][kk] = *reinterpret_cast<const short8*>(&Vs[buf][row * 64 + col]);
      }
#pragma unroll
    for (int mf = 0; mf < 2; ++mf) {
      short8 pa[2];
#pragma unroll
      for (int kk = 0; kk < 2; ++kk) {
        int row = mf * 16 + l15;
        int col = (kk * 32 + lg * 8) ^ ((row & 7) << 3);
        pa[kk] = *reinterpret_cast<const short8*>(&Ps[w][row * 64 + col]);
      }
#pragma unroll
      for (int ni = 0; ni < 4; ++ni) {
        oacc[mf][ni] = __builtin_amdgcn_mfma_f32_16x16x32_bf16(pa[0], vf[ni][0], oacc[mf][ni], 0, 0, 0);
        oacc[mf][ni] = __builtin_amdgcn_mfma_f32_16x16x32_bf16(pa[1], vf[ni][1], oacc[mf][ni], 0, 0, 0);
      }
    }
    __syncthreads();  // drains prefetch (vmcnt) + guards buf swap
  }

  // epilogue: ctx[b][s][h*64+d]
  int b = bh >> 4, h = bh & 15;
#pragma unroll
  for (int mf = 0; mf < 2; ++mf)
#pragma unroll
    for (int ni = 0; ni < 4; ++ni) {
      int d = ni * 16 + l15;
#pragma unroll
      for (int r = 0; r < 4; ++r) {
        int qr = q0 + w * 32 + mf * 16 + lg * 4 + r;
        float val = oacc[mf][ni][r] / lrow[mf][r];
        ctx[((size_t)(b * SEQ + qr)) * D_MODEL + h * HD + d] = f2bf(val);
      }
    }
}

// ---------------- output projection GEMM (bf16 ctx @ Wo + bo -> fp32) ----------------
__global__ __launch_bounds__(256) void out_gemm_kernel(const unsigned short* __restrict__ A,
                                                       const unsigned short* __restrict__ Bt,
                                                       const float* __restrict__ bias,
                                                       float* __restrict__ Out) {
  __shared__ unsigned short As[128 * 64];
  __shared__ unsigned short Bs[128 * 64];

  int m0 = blockIdx.x * 128, n0 = blockIdx.y * 128;
  int tid = threadIdx.x;
  int lane = tid & 63;
  int w = tid >> 6;
  int wr = (w >> 1) * 64, wc = (w & 1) * 64;
  int l15 = lane & 15, lg = lane >> 4;
  int lr8 = lane >> 3, lc8 = lane & 7;

  floatx4 acc[4][4];
#pragma unroll
  for (int mi = 0; mi < 4; ++mi)
#pragma unroll
    for (int ni = 0; ni < 4; ++ni)
#pragma unroll
      for (int e = 0; e < 4; ++e) acc[mi][ni][e] = 0.0f;

  for (int kt = 0; kt < D_MODEL / 64; ++kt) {
    int k0 = kt * 64;
#pragma unroll
    for (int i = 0; i < 4; ++i) {
      int c = w + i * 4;
      int r = c * 8 + lr8;
      int blk = lc8 ^ (r & 7);
      gl_lds16(&A[(size_t)(m0 + r) * D_MODEL + k0 + blk * 8], &As[c * 512]);
      gl_lds16(&Bt[(size_t)(n0 + r) * D_MODEL + k0 + blk * 8], &Bs[c * 512]);
    }
    __syncthreads();
#pragma unroll
    for (int kk = 0; kk < 2; ++kk) {
      short8 af[4], bf[4];
#pragma unroll
      for (int mi = 0; mi < 4; ++mi) {
        int row = wr + mi * 16 + l15;
        int col = (kk * 32 + lg * 8) ^ ((row & 7) << 3);
        af[mi] = *reinterpret_cast<const short8*>(&As[row * 64 + col]);
      }
#pragma unroll
      for (int ni = 0; ni < 4; ++ni) {
        int row = wc + ni * 16 + l15;
        int col = (kk * 32 + lg * 8) ^ ((row & 7) << 3);
        bf[ni] = *reinterpret_cast<const short8*>(&Bs[row * 64 + col]);
      }
#pragma unroll
      for (int mi = 0; mi < 4; ++mi)
#pragma unroll
        for (int ni = 0; ni < 4; ++ni)
          acc[mi][ni] =
              __builtin_amdgcn_mfma_f32_16x16x32_bf16(af[mi], bf[ni], acc[mi][ni], 0, 0, 0);
    }
    __syncthreads();
  }

#pragma unroll
  for (int mi = 0; mi < 4; ++mi)
#pragma unroll
    for (int ni = 0; ni < 4; ++ni) {
      int n = n0 + wc + ni * 16 + l15;
      float bia = bias[n];
#pragma unroll
      for (int r = 0; r < 4; ++r) {
        int m = m0 + wr + mi * 16 + lg * 4 + r;
        Out[(size_t)m * D_MODEL + n] = acc[mi][ni][r] + bia;
      }
    }
}

extern "C" void kernel_launch(void* const* d_in, const int* in_sizes, int n_in,
                              void* d_out, int out_size, void* d_ws, size_t ws_size,
                              hipStream_t stream) {
  const float* X  = (const float*)d_in[0];
  const float* Wq = (const float*)d_in[1];
  const float* bq = (const float*)d_in[2];
  const float* Wk = (const float*)d_in[3];
  const float* bk = (const float*)d_in[4];
  const float* Wv = (const float*)d_in[5];
  const float* bv = (const float*)d_in[6];
  const float* Wo = (const float*)d_in[7];
  const float* bo = (const float*)d_in[8];
  float* out = (float*)d_out;

  char* ws = (char*)d_ws;
  const size_t MB = 1024 * 1024;
  unsigned short* Xb   = (unsigned short*)(ws);
  unsigned short* WqT  = (unsigned short*)(ws + 16 * MB);
  unsigned short* WkT  = (unsigned short*)(ws + 18 * MB);
  unsigned short* WvT  = (unsigned short*)(ws + 20 * MB);
  unsigned short* WoT  = (unsigned short*)(ws + 22 * MB);
  unsigned short* Qw   = (unsigned short*)(ws + 24 * MB);
  unsigned short* Kw   = (unsigned short*)(ws + 40 * MB);
  unsigned short* Vtw  = (unsigned short*)(ws + 56 * MB);
  unsigned short* Ctx  = (unsigned short*)(ws + 72 * MB);

  cvt_x_kernel<<<(M_TOT * D_MODEL / 4) / 256, 256, 0, stream>>>(X, Xb);
  cvt_wt_kernel<<<dim3(16, 16, 4), 256, 0, stream>>>(Wq, Wk, Wv, Wo, WqT, WkT, WvT, WoT);
  qkv_gemm_kernel<<<dim3(M_TOT / 128, D_MODEL / 128, 3), 256, 0, stream>>>(
      Xb, WqT, WkT, WvT, bq, bk, bv, Qw, Kw, Vtw);
  attn_kernel<<<dim3(SEQ / 128, BATCH * NHEAD), 256, 0, stream>>>(Qw, Kw, Vtw, Ctx);
  out_gemm_kernel<<<dim3(M_TOT / 128, D_MODEL / 128), 256, 0, stream>>>(Ctx, WoT, bo, out);
}

// Round 4
// 360.662 us; speedup vs baseline: 1.2275x; 1.1762x over previous
//
#include <hip/hip_runtime.h>
#include <hip/hip_bf16.h>
#include <math.h>

typedef __attribute__((ext_vector_type(8))) short short8;
typedef __attribute__((ext_vector_type(4))) float floatx4;
typedef __attribute__((ext_vector_type(16))) float floatx16;

#define D_MODEL 1024
#define NHEAD   16
#define HD      64
#define BATCH   4
#define SEQ     2048
#define M_TOT   (BATCH * SEQ)  // 8192

__device__ __forceinline__ unsigned short f2bf(float f) {
  unsigned int u = __builtin_bit_cast(unsigned int, f);
  u += 0x7FFFu + ((u >> 16) & 1u);
  return (unsigned short)(u >> 16);
}

// pack 2 f32 -> 1 dword of 2 bf16 (lo=a, hi=b)
__device__ __forceinline__ unsigned pk2(float a, float b) {
  unsigned r;
  asm("v_cvt_pk_bf16_f32 %0, %1, %2" : "=v"(r) : "v"(a), "v"(b));
  return r;
}

__device__ __forceinline__ void gl_lds16(const void* g, void* l) {
  __builtin_amdgcn_global_load_lds((__attribute__((address_space(1))) void*)g,
                                   (__attribute__((address_space(3))) void*)l,
                                   16, 0, 0);
}

// ---------------- convert X (fp32 -> bf16) ----------------
__global__ __launch_bounds__(256) void cvt_x_kernel(const float* __restrict__ X,
                                                    unsigned short* __restrict__ Xb) {
  int i = blockIdx.x * 256 + threadIdx.x;
  float4 v = reinterpret_cast<const float4*>(X)[i];
  ushort4 o;
  o.x = f2bf(v.x); o.y = f2bf(v.y); o.z = f2bf(v.z); o.w = f2bf(v.w);
  reinterpret_cast<ushort4*>(Xb)[i] = o;
}

// ---------------- convert + transpose W (fp32 [K][N] -> bf16 [N][K]) ----------------
__global__ __launch_bounds__(256) void cvt_wt_kernel(const float* __restrict__ W0,
                                                     const float* __restrict__ W1,
                                                     const float* __restrict__ W2,
                                                     const float* __restrict__ W3,
                                                     unsigned short* __restrict__ T0,
                                                     unsigned short* __restrict__ T1,
                                                     unsigned short* __restrict__ T2,
                                                     unsigned short* __restrict__ T3) {
  const float* W;
  unsigned short* T;
  switch (blockIdx.z) {
    case 0: W = W0; T = T0; break;
    case 1: W = W1; T = T1; break;
    case 2: W = W2; T = T2; break;
    default: W = W3; T = T3; break;
  }
  __shared__ unsigned short tile[64][65];
  int n0 = blockIdx.x * 64, k0 = blockIdx.y * 64;
#pragma unroll
  for (int i = 0; i < 16; ++i) {
    int e = threadIdx.x + i * 256;
    int r = e >> 6, c = e & 63;
    tile[r][c] = f2bf(W[(size_t)(k0 + r) * D_MODEL + n0 + c]);
  }
  __syncthreads();
#pragma unroll
  for (int i = 0; i < 16; ++i) {
    int e = threadIdx.x + i * 256;
    int r = e >> 6, c = e & 63;
    T[(size_t)(n0 + r) * D_MODEL + k0 + c] = tile[c][r];
  }
}

// ---------------- fused QKV GEMM (unchanged) ----------------
__global__ __launch_bounds__(256) void qkv_gemm_kernel(
    const unsigned short* __restrict__ Xb,
    const unsigned short* __restrict__ WqT, const unsigned short* __restrict__ WkT,
    const unsigned short* __restrict__ WvT,
    const float* __restrict__ bq, const float* __restrict__ bk, const float* __restrict__ bv,
    unsigned short* __restrict__ Qo, unsigned short* __restrict__ Ko,
    unsigned short* __restrict__ Vo) {
  const unsigned short* Bt;
  const float* bias;
  unsigned short* Out;
  float scale;
  // Q pre-scaled by (1/8)*log2(e) for exp2-domain softmax
  if (blockIdx.z == 0)      { Bt = WqT; bias = bq; Out = Qo; scale = 0.18033688f; }
  else if (blockIdx.z == 1) { Bt = WkT; bias = bk; Out = Ko; scale = 1.0f; }
  else                      { Bt = WvT; bias = bv; Out = Vo; scale = 1.0f; }

  __shared__ unsigned short As[128 * 64];
  __shared__ unsigned short Bs[128 * 64];

  int m0 = blockIdx.x * 128, n0 = blockIdx.y * 128;
  int tid = threadIdx.x;
  int lane = tid & 63;
  int w = tid >> 6;
  int wr = (w >> 1) * 64, wc = (w & 1) * 64;
  int l15 = lane & 15, lg = lane >> 4;
  int lr8 = lane >> 3, lc8 = lane & 7;

  floatx4 acc[4][4];
#pragma unroll
  for (int mi = 0; mi < 4; ++mi)
#pragma unroll
    for (int ni = 0; ni < 4; ++ni)
#pragma unroll
      for (int e = 0; e < 4; ++e) acc[mi][ni][e] = 0.0f;

  for (int kt = 0; kt < D_MODEL / 64; ++kt) {
    int k0 = kt * 64;
#pragma unroll
    for (int i = 0; i < 4; ++i) {
      int c = w + i * 4;
      int r = c * 8 + lr8;
      int blk = lc8 ^ (r & 7);
      gl_lds16(&Xb[(size_t)(m0 + r) * D_MODEL + k0 + blk * 8], &As[c * 512]);
      gl_lds16(&Bt[(size_t)(n0 + r) * D_MODEL + k0 + blk * 8], &Bs[c * 512]);
    }
    __syncthreads();
#pragma unroll
    for (int kk = 0; kk < 2; ++kk) {
      short8 af[4], bf[4];
#pragma unroll
      for (int mi = 0; mi < 4; ++mi) {
        int row = wr + mi * 16 + l15;
        int col = (kk * 32 + lg * 8) ^ ((row & 7) << 3);
        af[mi] = *reinterpret_cast<const short8*>(&As[row * 64 + col]);
      }
#pragma unroll
      for (int ni = 0; ni < 4; ++ni) {
        int row = wc + ni * 16 + l15;
        int col = (kk * 32 + lg * 8) ^ ((row & 7) << 3);
        bf[ni] = *reinterpret_cast<const short8*>(&Bs[row * 64 + col]);
      }
#pragma unroll
      for (int mi = 0; mi < 4; ++mi)
#pragma unroll
        for (int ni = 0; ni < 4; ++ni)
          acc[mi][ni] =
              __builtin_amdgcn_mfma_f32_16x16x32_bf16(af[mi], bf[ni], acc[mi][ni], 0, 0, 0);
    }
    __syncthreads();
  }

  bool vout = (blockIdx.z == 2);
#pragma unroll
  for (int mi = 0; mi < 4; ++mi)
#pragma unroll
    for (int ni = 0; ni < 4; ++ni) {
      int n = n0 + wc + ni * 16 + l15;
      float bia = bias[n];
      int h = n >> 6, d = n & 63;
#pragma unroll
      for (int r = 0; r < 4; ++r) {
        int m = m0 + wr + mi * 16 + lg * 4 + r;
        int b = m >> 11, s = m & 2047;
        float val = (acc[mi][ni][r] + bia) * scale;
        size_t idx;
        if (vout)
          idx = (((size_t)(b * NHEAD + h)) * HD + d) * SEQ + s;   // V^T: [bh][d][s]
        else
          idx = (((size_t)(b * NHEAD + h)) * SEQ + s) * HD + d;   // Q,K: [bh][s][d]
        Out[idx] = f2bf(val);
      }
    }
}

// ---------------- causal flash attention: swapped 32x32, in-register softmax ----
// Q,K: [B*H][S][64] bf16 (Q pre-scaled (1/8)*log2e); Vt: [B*H][64][S]; ctx: [B][S][D].
__global__ __launch_bounds__(256) void attn_kernel(const unsigned short* __restrict__ Q,
                                                   const unsigned short* __restrict__ K,
                                                   const unsigned short* __restrict__ Vt,
                                                   unsigned short* __restrict__ ctx) {
  __shared__ unsigned short Ks[2][64 * 64];
  __shared__ unsigned short Vs[2][64 * 64];   // Vs[d][key]

  int qt = (int)gridDim.x - 1 - (int)blockIdx.x;  // longest blocks first
  int bh = blockIdx.y;
  int q0 = qt * 128;
  int tid = threadIdx.x;
  int lane = tid & 63;
  int w = tid >> 6;
  int l31 = lane & 31;
  int hi = lane >> 5;
  int lr8 = lane >> 3, lc8 = lane & 7;

  const unsigned short* Qb = Q + (size_t)bh * SEQ * HD;
  const unsigned short* Kb = K + (size_t)bh * SEQ * HD;
  const unsigned short* Vb = Vt + (size_t)bh * HD * SEQ;

  // Q B-fragments: wave w owns q rows q0+w*32 .. +31; lane holds q = l31, k = kc*16+hi*8..+7
  int myq = q0 + w * 32 + l31;
  short8 qf[4];
#pragma unroll
  for (int kc = 0; kc < 4; ++kc)
    qf[kc] = *reinterpret_cast<const short8*>(&Qb[(size_t)myq * HD + kc * 16 + hi * 8]);

  floatx16 oacc[2];
#pragma unroll
  for (int db = 0; db < 2; ++db)
#pragma unroll
    for (int r = 0; r < 16; ++r) oacc[db][r] = 0.0f;
  float mrow = -INFINITY;  // log2 domain, per lane's q-row (l31)
  float lrow = 0.0f;

  int nt = 2 * qt + 2;

  // prologue: stage tile 0 into buf 0
#pragma unroll
  for (int i = 0; i < 2; ++i) {
    int c = w + i * 4;
    int r = c * 8 + lr8;
    int blk = lc8 ^ (r & 7);
    gl_lds16(&Kb[(size_t)r * HD + blk * 8], &Ks[0][c * 512]);
    gl_lds16(&Vb[(size_t)r * SEQ + blk * 8], &Vs[0][c * 512]);
  }
  __syncthreads();

  for (int t = 0; t < nt; ++t) {
    int buf = t & 1;
    if (t + 1 < nt) {
      int kb1 = (t + 1) * 64;
      const unsigned short* kg = Kb + (size_t)kb1 * HD;
      const unsigned short* vg = Vb + kb1;
#pragma unroll
      for (int i = 0; i < 2; ++i) {
        int c = w + i * 4;
        int r = c * 8 + lr8;
        int blk = lc8 ^ (r & 7);
        gl_lds16(&kg[(size_t)r * HD + blk * 8], &Ks[buf ^ 1][c * 512]);
        gl_lds16(&vg[(size_t)r * SEQ + blk * 8], &Vs[buf ^ 1][c * 512]);
      }
    }

    // ---- QK^T (swapped): sfT[kb] = K_tile(32 keys) x Q^T; lane: q=l31, key r->(r&3)+8(r>>2)+4hi
    floatx16 sfT[2];
#pragma unroll
    for (int kb = 0; kb < 2; ++kb) {
#pragma unroll
      for (int r = 0; r < 16; ++r) sfT[kb][r] = 0.0f;
#pragma unroll
      for (int kc = 0; kc < 4; ++kc) {
        int row = kb * 32 + l31;
        int col = (kc * 16 + hi * 8) ^ ((row & 7) << 3);
        short8 kf = *reinterpret_cast<const short8*>(&Ks[buf][row * 64 + col]);
        sfT[kb] = __builtin_amdgcn_mfma_f32_32x32x16_bf16(kf, qf[kc], sfT[kb], 0, 0, 0);
      }
    }

    // causal mask (only the last two tiles straddle the diagonal)
    if (t >= nt - 2) {
      int kb0 = t * 64;
#pragma unroll
      for (int kb = 0; kb < 2; ++kb)
#pragma unroll
        for (int r = 0; r < 16; ++r) {
          int key = kb0 + kb * 32 + (r & 3) + 8 * (r >> 2) + 4 * hi;
          if (key > myq) sfT[kb][r] = -INFINITY;
        }
    }

    // ---- in-register online softmax (per lane: its q-row) ----
    float tm[16];
#pragma unroll
    for (int r = 0; r < 16; ++r) tm[r] = fmaxf(sfT[0][r], sfT[1][r]);
#pragma unroll
    for (int s = 8; s > 0; s >>= 1)
#pragma unroll
      for (int r = 0; r < 8; ++r)
        if (r < s) tm[r] = fmaxf(tm[r], tm[r + s]);
    float pm = fmaxf(tm[0], __shfl_xor(tm[0], 32));

    // defer-max: rescale only when max grew > 11.5 (log2 units ~ e^8)
    if (__any(pm > mrow + 11.5f)) {
      float nm = fmaxf(mrow, pm);
      float sc = exp2f(mrow - nm);
      mrow = nm;
      lrow *= sc;
      int base32 = lane & 32;
#pragma unroll
      for (int r = 0; r < 16; ++r) {
        int q31 = (r & 3) + 8 * (r >> 2) + 4 * hi;
        float sr = __shfl(sc, base32 + q31);
        oacc[0][r] *= sr;
        oacc[1][r] *= sr;
      }
    }

    // P = 2^(s - mrow), in place; row-sum
    float ts = 0.0f;
#pragma unroll
    for (int kb = 0; kb < 2; ++kb)
#pragma unroll
      for (int r = 0; r < 16; ++r) {
        float pe = exp2f(sfT[kb][r] - mrow);
        sfT[kb][r] = pe;
        ts += pe;
      }
    ts += __shfl_xor(ts, 32);
    lrow += ts;

    // ---- P -> A-fragments in-register (pack + cross-half exchange) + PV ----
#pragma unroll
    for (int kb = 0; kb < 2; ++kb) {
      unsigned D[8];
#pragma unroll
      for (int m = 0; m < 8; ++m) D[m] = pk2(sfT[kb][2 * m], sfT[kb][2 * m + 1]);
#pragma unroll
      for (int c = 0; c < 2; ++c) {
        unsigned send0 = hi ? D[4 * c] : D[4 * c + 2];
        unsigned send1 = hi ? D[4 * c + 1] : D[4 * c + 3];
        unsigned recv0 = (unsigned)__shfl_xor((int)send0, 32);
        unsigned recv1 = (unsigned)__shfl_xor((int)send1, 32);
        uint4 u;
        u.x = hi ? recv0 : D[4 * c];
        u.y = hi ? recv1 : D[4 * c + 1];
        u.z = hi ? D[4 * c + 2] : recv0;
        u.w = hi ? D[4 * c + 3] : recv1;
        short8 pa = __builtin_bit_cast(short8, u);
        int kc = kb * 2 + c;
#pragma unroll
        for (int db = 0; db < 2; ++db) {
          int row = db * 32 + l31;  // d
          int col = (kc * 16 + hi * 8) ^ ((row & 7) << 3);
          short8 vf = *reinterpret_cast<const short8*>(&Vs[buf][row * 64 + col]);
          oacc[db] = __builtin_amdgcn_mfma_f32_32x32x16_bf16(pa, vf, oacc[db], 0, 0, 0);
        }
      }
    }
    __syncthreads();  // drains prefetch + guards buf swap
  }

  // epilogue: redistribute lrow (softmax layout q=l31 -> D-frag rows), write ctx
  int b = bh >> 4, h = bh & 15;
  int base32 = lane & 32;
  float lrowD[16];
#pragma unroll
  for (int r = 0; r < 16; ++r) {
    int q31 = (r & 3) + 8 * (r >> 2) + 4 * hi;
    lrowD[r] = __shfl(lrow, base32 + q31);
  }
#pragma unroll
  for (int db = 0; db < 2; ++db) {
    int d = db * 32 + l31;
#pragma unroll
    for (int r = 0; r < 16; ++r) {
      int qr = q0 + w * 32 + (r & 3) + 8 * (r >> 2) + 4 * hi;
      float val = oacc[db][r] / lrowD[r];
      ctx[((size_t)(b * SEQ + qr)) * D_MODEL + h * HD + d] = f2bf(val);
    }
  }
}

// ---------------- output projection GEMM (unchanged) ----------------
__global__ __launch_bounds__(256) void out_gemm_kernel(const unsigned short* __restrict__ A,
                                                       const unsigned short* __restrict__ Bt,
                                                       const float* __restrict__ bias,
                                                       float* __restrict__ Out) {
  __shared__ unsigned short As[128 * 64];
  __shared__ unsigned short Bs[128 * 64];

  int m0 = blockIdx.x * 128, n0 = blockIdx.y * 128;
  int tid = threadIdx.x;
  int lane = tid & 63;
  int w = tid >> 6;
  int wr = (w >> 1) * 64, wc = (w & 1) * 64;
  int l15 = lane & 15, lg = lane >> 4;
  int lr8 = lane >> 3, lc8 = lane & 7;

  floatx4 acc[4][4];
#pragma unroll
  for (int mi = 0; mi < 4; ++mi)
#pragma unroll
    for (int ni = 0; ni < 4; ++ni)
#pragma unroll
      for (int e = 0; e < 4; ++e) acc[mi][ni][e] = 0.0f;

  for (int kt = 0; kt < D_MODEL / 64; ++kt) {
    int k0 = kt * 64;
#pragma unroll
    for (int i = 0; i < 4; ++i) {
      int c = w + i * 4;
      int r = c * 8 + lr8;
      int blk = lc8 ^ (r & 7);
      gl_lds16(&A[(size_t)(m0 + r) * D_MODEL + k0 + blk * 8], &As[c * 512]);
      gl_lds16(&Bt[(size_t)(n0 + r) * D_MODEL + k0 + blk * 8], &Bs[c * 512]);
    }
    __syncthreads();
#pragma unroll
    for (int kk = 0; kk < 2; ++kk) {
      short8 af[4], bf[4];
#pragma unroll
      for (int mi = 0; mi < 4; ++mi) {
        int row = wr + mi * 16 + l15;
        int col = (kk * 32 + lg * 8) ^ ((row & 7) << 3);
        af[mi] = *reinterpret_cast<const short8*>(&As[row * 64 + col]);
      }
#pragma unroll
      for (int ni = 0; ni < 4; ++ni) {
        int row = wc + ni * 16 + l15;
        int col = (kk * 32 + lg * 8) ^ ((row & 7) << 3);
        bf[ni] = *reinterpret_cast<const short8*>(&Bs[row * 64 + col]);
      }
#pragma unroll
      for (int mi = 0; mi < 4; ++mi)
#pragma unroll
        for (int ni = 0; ni < 4; ++ni)
          acc[mi][ni] =
              __builtin_amdgcn_mfma_f32_16x16x32_bf16(af[mi], bf[ni], acc[mi][ni], 0, 0, 0);
    }
    __syncthreads();
  }

#pragma unroll
  for (int mi = 0; mi < 4; ++mi)
#pragma unroll
    for (int ni = 0; ni < 4; ++ni) {
      int n = n0 + wc + ni * 16 + l15;
      float bia = bias[n];
#pragma unroll
      for (int r = 0; r < 4; ++r) {
        int m = m0 + wr + mi * 16 + lg * 4 + r;
        Out[(size_t)m * D_MODEL + n] = acc[mi][ni][r] + bia;
      }
    }
}

extern "C" void kernel_launch(void* const* d_in, const int* in_sizes, int n_in,
                              void* d_out, int out_size, void* d_ws, size_t ws_size,
                              hipStream_t stream) {
  const float* X  = (const float*)d_in[0];
  const float* Wq = (const float*)d_in[1];
  const float* bq = (const float*)d_in[2];
  const float* Wk = (const float*)d_in[3];
  const float* bk = (const float*)d_in[4];
  const float* Wv = (const float*)d_in[5];
  const float* bv = (const float*)d_in[6];
  const float* Wo = (const float*)d_in[7];
  const float* bo = (const float*)d_in[8];
  float* out = (float*)d_out;

  char* ws = (char*)d_ws;
  const size_t MB = 1024 * 1024;
  unsigned short* Xb   = (unsigned short*)(ws);
  unsigned short* WqT  = (unsigned short*)(ws + 16 * MB);
  unsigned short* WkT  = (unsigned short*)(ws + 18 * MB);
  unsigned short* WvT  = (unsigned short*)(ws + 20 * MB);
  unsigned short* WoT  = (unsigned short*)(ws + 22 * MB);
  unsigned short* Qw   = (unsigned short*)(ws + 24 * MB);
  unsigned short* Kw   = (unsigned short*)(ws + 40 * MB);
  unsigned short* Vtw  = (unsigned short*)(ws + 56 * MB);
  unsigned short* Ctx  = (unsigned short*)(ws + 72 * MB);

  cvt_x_kernel<<<(M_TOT * D_MODEL / 4) / 256, 256, 0, stream>>>(X, Xb);
  cvt_wt_kernel<<<dim3(16, 16, 4), 256, 0, stream>>>(Wq, Wk, Wv, Wo, WqT, WkT, WvT, WoT);
  qkv_gemm_kernel<<<dim3(M_TOT / 128, D_MODEL / 128, 3), 256, 0, stream>>>(
      Xb, WqT, WkT, WvT, bq, bk, bv, Qw, Kw, Vtw);
  attn_kernel<<<dim3(SEQ / 128, BATCH * NHEAD), 256, 0, stream>>>(Qw, Kw, Vtw, Ctx);
  out_gemm_kernel<<<dim3(M_TOT / 128, D_MODEL / 128), 256, 0, stream>>>(Ctx, WoT, bo, out);
}

// Round 6
// 297.469 us; speedup vs baseline: 1.4882x; 1.2124x over previous
//
#include <hip/hip_runtime.h>
#include <hip/hip_bf16.h>
#include <math.h>

typedef __attribute__((ext_vector_type(8))) short short8;
typedef __attribute__((ext_vector_type(4))) float floatx4;
typedef __attribute__((ext_vector_type(16))) float floatx16;

#define D_MODEL 1024
#define NHEAD   16
#define HD      64
#define BATCH   4
#define SEQ     2048
#define M_TOT   (BATCH * SEQ)  // 8192

__device__ __forceinline__ unsigned short f2bf(float f) {
  unsigned int u = __builtin_bit_cast(unsigned int, f);
  u += 0x7FFFu + ((u >> 16) & 1u);
  return (unsigned short)(u >> 16);
}

__device__ __forceinline__ unsigned pk2(float a, float b) {
  unsigned r;
  asm("v_cvt_pk_bf16_f32 %0, %1, %2" : "=v"(r) : "v"(a), "v"(b));
  return r;
}

__device__ __forceinline__ void gl_lds16(const void* g, void* l) {
  __builtin_amdgcn_global_load_lds((__attribute__((address_space(1))) void*)g,
                                   (__attribute__((address_space(3))) void*)l,
                                   16, 0, 0);
}

// attn LDS swizzle: distinct slot permutation for rows r, r+8, r+16, r+24
__device__ __forceinline__ int aswz(int r) { return (r ^ (r >> 3)) & 7; }

// ---------------- convert X (fp32 -> bf16) ----------------
__global__ __launch_bounds__(256) void cvt_x_kernel(const float* __restrict__ X,
                                                    unsigned short* __restrict__ Xb) {
  int i = blockIdx.x * 256 + threadIdx.x;
  float4 v = reinterpret_cast<const float4*>(X)[i];
  ushort4 o;
  o.x = f2bf(v.x); o.y = f2bf(v.y); o.z = f2bf(v.z); o.w = f2bf(v.w);
  reinterpret_cast<ushort4*>(Xb)[i] = o;
}

// ---------------- convert + transpose W (fp32 [K][N] -> bf16 [N][K]) ----------------
__global__ __launch_bounds__(256) void cvt_wt_kernel(const float* __restrict__ W0,
                                                     const float* __restrict__ W1,
                                                     const float* __restrict__ W2,
                                                     const float* __restrict__ W3,
                                                     unsigned short* __restrict__ T0,
                                                     unsigned short* __restrict__ T1,
                                                     unsigned short* __restrict__ T2,
                                                     unsigned short* __restrict__ T3) {
  const float* W;
  unsigned short* T;
  switch (blockIdx.z) {
    case 0: W = W0; T = T0; break;
    case 1: W = W1; T = T1; break;
    case 2: W = W2; T = T2; break;
    default: W = W3; T = T3; break;
  }
  __shared__ unsigned short tile[64][65];
  int n0 = blockIdx.x * 64, k0 = blockIdx.y * 64;
#pragma unroll
  for (int i = 0; i < 16; ++i) {
    int e = threadIdx.x + i * 256;
    int r = e >> 6, c = e & 63;
    tile[r][c] = f2bf(W[(size_t)(k0 + r) * D_MODEL + n0 + c]);
  }
  __syncthreads();
#pragma unroll
  for (int i = 0; i < 16; ++i) {
    int e = threadIdx.x + i * 256;
    int r = e >> 6, c = e & 63;
    T[(size_t)(n0 + r) * D_MODEL + k0 + c] = tile[c][r];
  }
}

// ---------------- fused QKV GEMM (unchanged) ----------------
__global__ __launch_bounds__(256) void qkv_gemm_kernel(
    const unsigned short* __restrict__ Xb,
    const unsigned short* __restrict__ WqT, const unsigned short* __restrict__ WkT,
    const unsigned short* __restrict__ WvT,
    const float* __restrict__ bq, const float* __restrict__ bk, const float* __restrict__ bv,
    unsigned short* __restrict__ Qo, unsigned short* __restrict__ Ko,
    unsigned short* __restrict__ Vo) {
  const unsigned short* Bt;
  const float* bias;
  unsigned short* Out;
  float scale;
  // Q pre-scaled by (1/8)*log2(e) for exp2-domain softmax
  if (blockIdx.z == 0)      { Bt = WqT; bias = bq; Out = Qo; scale = 0.18033688f; }
  else if (blockIdx.z == 1) { Bt = WkT; bias = bk; Out = Ko; scale = 1.0f; }
  else                      { Bt = WvT; bias = bv; Out = Vo; scale = 1.0f; }

  __shared__ unsigned short As[128 * 64];
  __shared__ unsigned short Bs[128 * 64];

  int m0 = blockIdx.x * 128, n0 = blockIdx.y * 128;
  int tid = threadIdx.x;
  int lane = tid & 63;
  int w = tid >> 6;
  int wr = (w >> 1) * 64, wc = (w & 1) * 64;
  int l15 = lane & 15, lg = lane >> 4;
  int lr8 = lane >> 3, lc8 = lane & 7;

  floatx4 acc[4][4];
#pragma unroll
  for (int mi = 0; mi < 4; ++mi)
#pragma unroll
    for (int ni = 0; ni < 4; ++ni)
#pragma unroll
      for (int e = 0; e < 4; ++e) acc[mi][ni][e] = 0.0f;

  for (int kt = 0; kt < D_MODEL / 64; ++kt) {
    int k0 = kt * 64;
#pragma unroll
    for (int i = 0; i < 4; ++i) {
      int c = w + i * 4;
      int r = c * 8 + lr8;
      int blk = lc8 ^ (r & 7);
      gl_lds16(&Xb[(size_t)(m0 + r) * D_MODEL + k0 + blk * 8], &As[c * 512]);
      gl_lds16(&Bt[(size_t)(n0 + r) * D_MODEL + k0 + blk * 8], &Bs[c * 512]);
    }
    __syncthreads();
#pragma unroll
    for (int kk = 0; kk < 2; ++kk) {
      short8 af[4], bf[4];
#pragma unroll
      for (int mi = 0; mi < 4; ++mi) {
        int row = wr + mi * 16 + l15;
        int col = (kk * 32 + lg * 8) ^ ((row & 7) << 3);
        af[mi] = *reinterpret_cast<const short8*>(&As[row * 64 + col]);
      }
#pragma unroll
      for (int ni = 0; ni < 4; ++ni) {
        int row = wc + ni * 16 + l15;
        int col = (kk * 32 + lg * 8) ^ ((row & 7) << 3);
        bf[ni] = *reinterpret_cast<const short8*>(&Bs[row * 64 + col]);
      }
#pragma unroll
      for (int mi = 0; mi < 4; ++mi)
#pragma unroll
        for (int ni = 0; ni < 4; ++ni)
          acc[mi][ni] =
              __builtin_amdgcn_mfma_f32_16x16x32_bf16(af[mi], bf[ni], acc[mi][ni], 0, 0, 0);
    }
    __syncthreads();
  }

  bool vout = (blockIdx.z == 2);
#pragma unroll
  for (int mi = 0; mi < 4; ++mi)
#pragma unroll
    for (int ni = 0; ni < 4; ++ni) {
      int n = n0 + wc + ni * 16 + l15;
      float bia = bias[n];
      int h = n >> 6, d = n & 63;
#pragma unroll
      for (int r = 0; r < 4; ++r) {
        int m = m0 + wr + mi * 16 + lg * 4 + r;
        int b = m >> 11, s = m & 2047;
        float val = (acc[mi][ni][r] + bia) * scale;
        size_t idx;
        if (vout)
          idx = (((size_t)(b * NHEAD + h)) * HD + d) * SEQ + s;   // V^T: [bh][d][s]
        else
          idx = (((size_t)(b * NHEAD + h)) * SEQ + s) * HD + d;   // Q,K: [bh][s][d]
        Out[idx] = f2bf(val);
      }
    }
}

// ---------------- causal flash attention: swapped 32x32, paired q-tiles ----
// Q,K: [B*H][S][64] bf16 (Q pre-scaled (1/8)*log2e); Vt: [B*H][64][S]; ctx: [B][S][D].
// Block x handles q-tiles {x, 15-x} (128 rows each) -> uniform 34 key-tiles/block.
__global__ __launch_bounds__(256) void attn_kernel(const unsigned short* __restrict__ Q,
                                                   const unsigned short* __restrict__ K,
                                                   const unsigned short* __restrict__ Vt,
                                                   unsigned short* __restrict__ ctx) {
  __shared__ unsigned short Ks[2][64 * 64];
  __shared__ unsigned short Vs[2][64 * 64];   // Vs[d][key]

  int bh = blockIdx.y;
  int tid = threadIdx.x;
  int lane = tid & 63;
  int w = tid >> 6;
  int l31 = lane & 31;
  int hi = lane >> 5;
  int lr8 = lane >> 3, lc8 = lane & 7;

  const unsigned short* Qb = Q + (size_t)bh * SEQ * HD;
  const unsigned short* Kb = K + (size_t)bh * SEQ * HD;
  const unsigned short* Vb = Vt + (size_t)bh * HD * SEQ;
  int b = bh >> 4, h = bh & 15;

  for (int ph = 0; ph < 2; ++ph) {
    int qt = (ph == 0) ? (int)blockIdx.x : 15 - (int)blockIdx.x;
    int q0 = qt * 128;
    int myq = q0 + w * 32 + l31;

    short8 qf[4];
#pragma unroll
    for (int kc = 0; kc < 4; ++kc)
      qf[kc] = *reinterpret_cast<const short8*>(&Qb[(size_t)myq * HD + kc * 16 + hi * 8]);

    floatx16 oacc[2];
#pragma unroll
    for (int db = 0; db < 2; ++db)
#pragma unroll
      for (int r = 0; r < 16; ++r) oacc[db][r] = 0.0f;
    float mrow = -INFINITY;  // log2 domain, per lane's q-row (l31)
    float lrow = 0.0f;

    int nt = 2 * qt + 2;

    // prologue: stage tile 0 into buf 0
#pragma unroll
    for (int i = 0; i < 2; ++i) {
      int c = w + i * 4;
      int r = c * 8 + lr8;
      int blk = lc8 ^ aswz(r);
      gl_lds16(&Kb[(size_t)r * HD + blk * 8], &Ks[0][c * 512]);
      gl_lds16(&Vb[(size_t)r * SEQ + blk * 8], &Vs[0][c * 512]);
    }
    __syncthreads();

    for (int t = 0; t < nt; ++t) {
      int buf = t & 1;
      if (t + 1 < nt) {
        int kb1 = (t + 1) * 64;
        const unsigned short* kg = Kb + (size_t)kb1 * HD;
        const unsigned short* vg = Vb + kb1;
#pragma unroll
        for (int i = 0; i < 2; ++i) {
          int c = w + i * 4;
          int r = c * 8 + lr8;
          int blk = lc8 ^ aswz(r);
          gl_lds16(&kg[(size_t)r * HD + blk * 8], &Ks[buf ^ 1][c * 512]);
          gl_lds16(&vg[(size_t)r * SEQ + blk * 8], &Vs[buf ^ 1][c * 512]);
        }
      }

      // ---- QK^T (swapped): lane holds q=l31; key r -> (r&3)+8*(r>>2)+4*hi
      floatx16 sfT[2];
#pragma unroll
      for (int kb = 0; kb < 2; ++kb) {
#pragma unroll
        for (int r = 0; r < 16; ++r) sfT[kb][r] = 0.0f;
#pragma unroll
        for (int kc = 0; kc < 4; ++kc) {
          int row = kb * 32 + l31;
          int col = (kc * 16 + hi * 8) ^ (aswz(row) << 3);
          short8 kf = *reinterpret_cast<const short8*>(&Ks[buf][row * 64 + col]);
          sfT[kb] = __builtin_amdgcn_mfma_f32_32x32x16_bf16(kf, qf[kc], sfT[kb], 0, 0, 0);
        }
      }

      // causal mask (only the last two tiles straddle the diagonal)
      if (t >= nt - 2) {
        int kb0 = t * 64;
#pragma unroll
        for (int kb = 0; kb < 2; ++kb)
#pragma unroll
          for (int r = 0; r < 16; ++r) {
            int key = kb0 + kb * 32 + (r & 3) + 8 * (r >> 2) + 4 * hi;
            if (key > myq) sfT[kb][r] = -INFINITY;
          }
      }

      // ---- in-register online softmax ----
      float tm[16];
#pragma unroll
      for (int r = 0; r < 16; ++r) tm[r] = fmaxf(sfT[0][r], sfT[1][r]);
#pragma unroll
      for (int s = 8; s > 0; s >>= 1)
#pragma unroll
        for (int r = 0; r < 8; ++r)
          if (r < s) tm[r] = fmaxf(tm[r], tm[r + s]);
      float pm = fmaxf(tm[0], __shfl_xor(tm[0], 32));

      // defer-max: rescale only when max grew > 11.5 (log2 units ~ e^8)
      if (__any(pm > mrow + 11.5f)) {
        float nm = fmaxf(mrow, pm);
        float sc = exp2f(mrow - nm);
        mrow = nm;
        lrow *= sc;
        int base32 = lane & 32;
#pragma unroll
        for (int r = 0; r < 16; ++r) {
          int q31 = (r & 3) + 8 * (r >> 2) + 4 * hi;
          float sr = __shfl(sc, base32 + q31);
          oacc[0][r] *= sr;
          oacc[1][r] *= sr;
        }
      }

      // P = 2^(s - mrow); row-sum
      float ts = 0.0f;
#pragma unroll
      for (int kb = 0; kb < 2; ++kb)
#pragma unroll
        for (int r = 0; r < 16; ++r) {
          float pe = exp2f(sfT[kb][r] - mrow);
          sfT[kb][r] = pe;
          ts += pe;
        }
      ts += __shfl_xor(ts, 32);
      lrow += ts;

      // ---- P -> A-fragments in-register + PV ----
#pragma unroll
      for (int kb = 0; kb < 2; ++kb) {
        unsigned D[8];
#pragma unroll
        for (int m = 0; m < 8; ++m) D[m] = pk2(sfT[kb][2 * m], sfT[kb][2 * m + 1]);
#pragma unroll
        for (int c = 0; c < 2; ++c) {
          unsigned send0 = hi ? D[4 * c] : D[4 * c + 2];
          unsigned send1 = hi ? D[4 * c + 1] : D[4 * c + 3];
          unsigned recv0 = (unsigned)__shfl_xor((int)send0, 32);
          unsigned recv1 = (unsigned)__shfl_xor((int)send1, 32);
          uint4 u;
          u.x = hi ? recv0 : D[4 * c];
          u.y = hi ? recv1 : D[4 * c + 1];
          u.z = hi ? D[4 * c + 2] : recv0;
          u.w = hi ? D[4 * c + 3] : recv1;
          short8 pa = __builtin_bit_cast(short8, u);
          int kc = kb * 2 + c;
#pragma unroll
          for (int db = 0; db < 2; ++db) {
            int row = db * 32 + l31;  // d
            int col = (kc * 16 + hi * 8) ^ (aswz(row) << 3);
            short8 vf = *reinterpret_cast<const short8*>(&Vs[buf][row * 64 + col]);
            oacc[db] = __builtin_amdgcn_mfma_f32_32x32x16_bf16(pa, vf, oacc[db], 0, 0, 0);
          }
        }
      }
      __syncthreads();  // drains prefetch + guards buf swap
    }

    // epilogue: redistribute lrow (q=l31 -> D-frag rows), write ctx
    int base32 = lane & 32;
    float lrowD[16];
#pragma unroll
    for (int r = 0; r < 16; ++r) {
      int q31 = (r & 3) + 8 * (r >> 2) + 4 * hi;
      lrowD[r] = __shfl(lrow, base32 + q31);
    }
#pragma unroll
    for (int db = 0; db < 2; ++db) {
      int d = db * 32 + l31;
#pragma unroll
      for (int r = 0; r < 16; ++r) {
        int qr = q0 + w * 32 + (r & 3) + 8 * (r >> 2) + 4 * hi;
        float val = oacc[db][r] / lrowD[r];
        ctx[((size_t)(b * SEQ + qr)) * D_MODEL + h * HD + d] = f2bf(val);
      }
    }
    __syncthreads();  // phase boundary: LDS reuse
  }
}

// ---------------- output projection GEMM (unchanged) ----------------
__global__ __launch_bounds__(256) void out_gemm_kernel(const unsigned short* __restrict__ A,
                                                       const unsigned short* __restrict__ Bt,
                                                       const float* __restrict__ bias,
                                                       float* __restrict__ Out) {
  __shared__ unsigned short As[128 * 64];
  __shared__ unsigned short Bs[128 * 64];

  int m0 = blockIdx.x * 128, n0 = blockIdx.y * 128;
  int tid = threadIdx.x;
  int lane = tid & 63;
  int w = tid >> 6;
  int wr = (w >> 1) * 64, wc = (w & 1) * 64;
  int l15 = lane & 15, lg = lane >> 4;
  int lr8 = lane >> 3, lc8 = lane & 7;

  floatx4 acc[4][4];
#pragma unroll
  for (int mi = 0; mi < 4; ++mi)
#pragma unroll
    for (int ni = 0; ni < 4; ++ni)
#pragma unroll
      for (int e = 0; e < 4; ++e) acc[mi][ni][e] = 0.0f;

  for (int kt = 0; kt < D_MODEL / 64; ++kt) {
    int k0 = kt * 64;
#pragma unroll
    for (int i = 0; i < 4; ++i) {
      int c = w + i * 4;
      int r = c * 8 + lr8;
      int blk = lc8 ^ (r & 7);
      gl_lds16(&A[(size_t)(m0 + r) * D_MODEL + k0 + blk * 8], &As[c * 512]);
      gl_lds16(&Bt[(size_t)(n0 + r) * D_MODEL + k0 + blk * 8], &Bs[c * 512]);
    }
    __syncthreads();
#pragma unroll
    for (int kk = 0; kk < 2; ++kk) {
      short8 af[4], bf[4];
#pragma unroll
      for (int mi = 0; mi < 4; ++mi) {
        int row = wr + mi * 16 + l15;
        int col = (kk * 32 + lg * 8) ^ ((row & 7) << 3);
        af[mi] = *reinterpret_cast<const short8*>(&As[row * 64 + col]);
      }
#pragma unroll
      for (int ni = 0; ni < 4; ++ni) {
        int row = wc + ni * 16 + l15;
        int col = (kk * 32 + lg * 8) ^ ((row & 7) << 3);
        bf[ni] = *reinterpret_cast<const short8*>(&Bs[row * 64 + col]);
      }
#pragma unroll
      for (int mi = 0; mi < 4; ++mi)
#pragma unroll
        for (int ni = 0; ni < 4; ++ni)
          acc[mi][ni] =
              __builtin_amdgcn_mfma_f32_16x16x32_bf16(af[mi], bf[ni], acc[mi][ni], 0, 0, 0);
    }
    __syncthreads();
  }

#pragma unroll
  for (int mi = 0; mi < 4; ++mi)
#pragma unroll
    for (int ni = 0; ni < 4; ++ni) {
      int n = n0 + wc + ni * 16 + l15;
      float bia = bias[n];
#pragma unroll
      for (int r = 0; r < 4; ++r) {
        int m = m0 + wr + mi * 16 + lg * 4 + r;
        Out[(size_t)m * D_MODEL + n] = acc[mi][ni][r] + bia;
      }
    }
}

extern "C" void kernel_launch(void* const* d_in, const int* in_sizes, int n_in,
                              void* d_out, int out_size, void* d_ws, size_t ws_size,
                              hipStream_t stream) {
  const float* X  = (const float*)d_in[0];
  const float* Wq = (const float*)d_in[1];
  const float* bq = (const float*)d_in[2];
  const float* Wk = (const float*)d_in[3];
  const float* bk = (const float*)d_in[4];
  const float* Wv = (const float*)d_in[5];
  const float* bv = (const float*)d_in[6];
  const float* Wo = (const float*)d_in[7];
  const float* bo = (const float*)d_in[8];
  float* out = (float*)d_out;

  char* ws = (char*)d_ws;
  const size_t MB = 1024 * 1024;
  unsigned short* Xb   = (unsigned short*)(ws);
  unsigned short* WqT  = (unsigned short*)(ws + 16 * MB);
  unsigned short* WkT  = (unsigned short*)(ws + 18 * MB);
  unsigned short* WvT  = (unsigned short*)(ws + 20 * MB);
  unsigned short* WoT  = (unsigned short*)(ws + 22 * MB);
  unsigned short* Qw   = (unsigned short*)(ws + 24 * MB);
  unsigned short* Kw   = (unsigned short*)(ws + 40 * MB);
  unsigned short* Vtw  = (unsigned short*)(ws + 56 * MB);
  unsigned short* Ctx  = (unsigned short*)(ws + 72 * MB);

  cvt_x_kernel<<<(M_TOT * D_MODEL / 4) / 256, 256, 0, stream>>>(X, Xb);
  cvt_wt_kernel<<<dim3(16, 16, 4), 256, 0, stream>>>(Wq, Wk, Wv, Wo, WqT, WkT, WvT, WoT);
  qkv_gemm_kernel<<<dim3(M_TOT / 128, D_MODEL / 128, 3), 256, 0, stream>>>(
      Xb, WqT, WkT, WvT, bq, bk, bv, Qw, Kw, Vtw);
  attn_kernel<<<dim3(8, BATCH * NHEAD), 256, 0, stream>>>(Qw, Kw, Vtw, Ctx);
  out_gemm_kernel<<<dim3(M_TOT / 128, D_MODEL / 128), 256, 0, stream>>>(Ctx, WoT, bo, out);
}